// Round 5
// baseline (565.501 us; speedup 1.0000x reference)
//
#include <hip/hip_runtime.h>
#include <cstdint>
#include <cstddef>

// VAE forward, fused bf16-MFMA pipeline.
// Sizes fixed: B=32768, INPUT=1024, HIDDEN=1024, LATENT=128.
//
// R5: (a) big GEMMs use 128x256 block tile, 4 waves x (64x128 acc = 4x8
//     16x16x32 tiles). MFMA:ds_read ratio 2.0 -> 2.67, addr-calc VALU
//     amortized over 2x MFMA. R4 showed MfmaUtil pinned at 25% w/ VALUBusy
//     50% -- per-iter overhead, not memory, is the limiter.
//     (b) cast fused into the prep kernel (one launch fewer).
// R4 (kept): BK=64; gemm2+zkl fusion.
// R3 (kept): XCD-pinned 1D grid decode (FETCH 298->90MB).
// R2 (kept): XOR-swizzled staging (LDS bank conflicts -> 0).

typedef __bf16 bf16x8 __attribute__((ext_vector_type(8)));
typedef float f32x4 __attribute__((ext_vector_type(4)));

__device__ __forceinline__ unsigned short f32_to_bf16(float f) {
  unsigned int u = __float_as_uint(f);
  u += 0x7fffu + ((u >> 16) & 1u);   // round-to-nearest-even (finite values)
  return (unsigned short)(u >> 16);
}

// ------------- fused prep: 5 transposes + x-cast in one kernel -------------
// blocks [0,2432): transpose jobs (32x32 tiles); [2432,4480): cast x (float4)
struct TransJob { const float* in; unsigned short* out; int K, N, blkEnd; };

__global__ void prep_k(TransJob j0, TransJob j1, TransJob j2, TransJob j3,
                       TransJob j4, const float* __restrict__ x,
                       unsigned short* __restrict__ xbf, int n4) {
  int bid = blockIdx.x;
  int tid = threadIdx.y * 32 + threadIdx.x;
  if (bid >= 2432) {
    int base = (bid - 2432) * 256 + tid;
    int stride = 2048 * 256;
#pragma unroll
    for (int it = 0; it < 16; ++it) {
      int i = base + it * stride;
      float4 v = reinterpret_cast<const float4*>(x)[i];
      ushort4 o = make_ushort4(f32_to_bf16(v.x), f32_to_bf16(v.y),
                               f32_to_bf16(v.z), f32_to_bf16(v.w));
      reinterpret_cast<ushort4*>(xbf)[i] = o;
    }
    return;
  }
  __shared__ float tile[32][33];
  TransJob j; int base;
  if (bid < j0.blkEnd)      { j = j0; base = 0; }
  else if (bid < j1.blkEnd) { j = j1; base = j0.blkEnd; }
  else if (bid < j2.blkEnd) { j = j2; base = j1.blkEnd; }
  else if (bid < j3.blkEnd) { j = j3; base = j2.blkEnd; }
  else                      { j = j4; base = j3.blkEnd; }
  int local = bid - base;
  int gxN = j.N >> 5;
  int n0 = (local % gxN) * 32, k0 = (local / gxN) * 32;
  int tx = threadIdx.x, ty = threadIdx.y;  // block is 32x8
#pragma unroll
  for (int r = 0; r < 32; r += 8)
    tile[ty + r][tx] = j.in[(size_t)(k0 + ty + r) * j.N + n0 + tx];
  __syncthreads();
#pragma unroll
  for (int r = 0; r < 32; r += 8)
    j.out[(size_t)(n0 + ty + r) * j.K + k0 + tx] = f32_to_bf16(tile[tx][ty + r]);
}

// async global->LDS, 16B per lane; LDS dest must be contiguous in lane order
__device__ __forceinline__ void gl_lds16(const unsigned short* g, unsigned short* l) {
  __builtin_amdgcn_global_load_lds(
      (__attribute__((address_space(1))) void*)g,
      (__attribute__((address_space(3))) void*)l, 16, 0, 0);
}

// ---------------- GEMM: C = A[M][K] @ BT[N][K]^T + bias ----------------
// 128x256 block tile, BK=64, 4 waves each 64 rows x 128 cols (4x8 acc).
// 1D grid, XCD-pinned decode (gx = N/256 col-blocks, gy row-blocks, gy%8==0).
// EPI 0: relu->bf16 to outb. EPI 2: bernoulli LL rowsum atomicAdd to outf.
template <int EPI>
__global__ __launch_bounds__(256) void gemm_bt(
    const unsigned short* __restrict__ A, const unsigned short* __restrict__ BT,
    int gx, int N, int K,
    const float* __restrict__ bias0,
    unsigned short* __restrict__ outb, float* __restrict__ outf,
    const unsigned short* __restrict__ xbf) {
  __shared__ __align__(16) unsigned short As[128 * 64];   // 16 KB
  __shared__ __align__(16) unsigned short Bs[256 * 64];   // 32 KB

  const int tid = threadIdx.x;
  const int lane = tid & 63;
  const int wave = tid >> 6;
  const int wr = wave & 1, wc = wave >> 1;   // wave tile: rows wr*64, cols wc*128
  const int bid = blockIdx.x;
  const int xcd = bid & 7;
  const int t8 = bid >> 3;
  const int m0 = (xcd + 8 * (t8 / gx)) * 128;
  const int n0 = (t8 % gx) * 256;
  const int lm = lane & 15, lq = lane >> 4;

  // staging: A 1024 chunks (4/thread), B 2048 chunks (8/thread);
  // LDS slot c&7 of row c>>3 holds global chunk (c&7)^(row&7)
  const unsigned short* agp[4];
  const unsigned short* bgp[8];
#pragma unroll
  for (int r = 0; r < 4; ++r) {
    int c = tid + 256 * r;
    int row = c >> 3, q = (c & 7) ^ (row & 7);
    agp[r] = A + (size_t)(m0 + row) * K + q * 8;
  }
#pragma unroll
  for (int r = 0; r < 8; ++r) {
    int c = tid + 256 * r;
    int row = c >> 3, q = (c & 7) ^ (row & 7);
    bgp[r] = BT + (size_t)(n0 + row) * K + q * 8;
  }
  const int sw = lm & 7;   // read-side swizzle

  f32x4 acc[4][8] = {};

  for (int kt = 0; kt < K; kt += 64) {
#pragma unroll
    for (int r = 0; r < 4; ++r) gl_lds16(agp[r] + kt, As + (tid + 256 * r) * 8);
#pragma unroll
    for (int r = 0; r < 8; ++r) gl_lds16(bgp[r] + kt, Bs + (tid + 256 * r) * 8);
    __syncthreads();

#pragma unroll
    for (int s = 0; s < 2; ++s) {
      const int so = ((s << 2) | lq) ^ sw;
      bf16x8 af[4], bfr[8];
#pragma unroll
      for (int i = 0; i < 4; ++i)
        af[i] = *reinterpret_cast<const bf16x8*>(As + (wr * 64 + i * 16 + lm) * 64 + so * 8);
#pragma unroll
      for (int j = 0; j < 8; ++j)
        bfr[j] = *reinterpret_cast<const bf16x8*>(Bs + (wc * 128 + j * 16 + lm) * 64 + so * 8);
#pragma unroll
      for (int i = 0; i < 4; ++i)
#pragma unroll
        for (int j = 0; j < 8; ++j)
          acc[i][j] = __builtin_amdgcn_mfma_f32_16x16x32_bf16(af[i], bfr[j], acc[i][j], 0, 0, 0);
    }
    __syncthreads();
  }

  if (EPI == 0) {
#pragma unroll
    for (int i = 0; i < 4; ++i)
#pragma unroll
      for (int j = 0; j < 8; ++j) {
        int col = n0 + wc * 128 + j * 16 + lm;
        float bias = bias0[col];
#pragma unroll
        for (int r = 0; r < 4; ++r) {
          int row = m0 + wr * 64 + i * 16 + lq * 4 + r;
          float v = acc[i][j][r] + bias;
          v = fmaxf(v, 0.f);
          outb[(size_t)row * N + col] = f32_to_bf16(v);
        }
      }
  } else {
#pragma unroll
    for (int i = 0; i < 4; ++i) {
      float rs[4] = {0.f, 0.f, 0.f, 0.f};
#pragma unroll
      for (int j = 0; j < 8; ++j) {
        int col = n0 + wc * 128 + j * 16 + lm;
        float bias = bias0[col];
#pragma unroll
        for (int r = 0; r < 4; ++r) {
          int row = m0 + wr * 64 + i * 16 + lq * 4 + r;
          float l = acc[i][j][r] + bias;
          unsigned short xb = xbf[(size_t)row * N + col];  // 0x0000 or 0x3F80
          float t = xb ? -l : l;
          float sp = fmaxf(t, 0.f) + __logf(1.f + __expf(-fabsf(t)));
          rs[r] -= sp;
        }
      }
#pragma unroll
      for (int off = 1; off < 16; off <<= 1)
#pragma unroll
        for (int r = 0; r < 4; ++r) rs[r] += __shfl_xor(rs[r], off, 64);
      if (lm == 0) {
#pragma unroll
        for (int r = 0; r < 4; ++r)
          atomicAdd(&outf[m0 + wr * 64 + i * 16 + lq * 4 + r], rs[r]);
      }
    }
  }
}

// -------- GEMM2+zkl fused: S2 = h @ w2t^T (N=256), z/kl in epilogue --------
// 128x256 tile per block, 4 waves each 32 rows x 256 cols; BK=64.
// acc[i][j]: mu at n-tile j (j<8), ls at j+8 -> same lane, no cross-lane.
__global__ __launch_bounds__(256, 1) void gemm2_zkl(
    const unsigned short* __restrict__ A,     // h [B][K]
    const unsigned short* __restrict__ BT,    // w2t [256][K]
    int K,
    const float* __restrict__ bmu, const float* __restrict__ bls,
    const float* __restrict__ eps,            // [B][128]
    unsigned short* __restrict__ z,           // [B][128] bf16
    float* __restrict__ out) {
  __shared__ __align__(16) unsigned short As[128 * 64];   // 16 KB
  __shared__ __align__(16) unsigned short Bs[256 * 64];   // 32 KB

  const int tid = threadIdx.x;
  const int lane = tid & 63;
  const int wave = tid >> 6;
  const int m0 = blockIdx.x * 128;
  const int lm = lane & 15, lq = lane >> 4;

  const unsigned short* agp[4];
  const unsigned short* bgp[8];
#pragma unroll
  for (int r = 0; r < 4; ++r) {
    int c = tid + 256 * r;
    int row = c >> 3, q = (c & 7) ^ (row & 7);
    agp[r] = A + (size_t)(m0 + row) * K + q * 8;
  }
#pragma unroll
  for (int r = 0; r < 8; ++r) {
    int c = tid + 256 * r;
    int row = c >> 3, q = (c & 7) ^ (row & 7);
    bgp[r] = BT + (size_t)row * K + q * 8;
  }
  const int sw = lm & 7;

  f32x4 acc[2][16] = {};

  for (int kt = 0; kt < K; kt += 64) {
#pragma unroll
    for (int r = 0; r < 4; ++r) gl_lds16(agp[r] + kt, As + (tid + 256 * r) * 8);
#pragma unroll
    for (int r = 0; r < 8; ++r) gl_lds16(bgp[r] + kt, Bs + (tid + 256 * r) * 8);
    __syncthreads();

#pragma unroll
    for (int s = 0; s < 2; ++s) {
      const int so = ((s << 2) | lq) ^ sw;
      bf16x8 af[2];
#pragma unroll
      for (int i = 0; i < 2; ++i)
        af[i] = *reinterpret_cast<const bf16x8*>(As + (wave * 32 + i * 16 + lm) * 64 + so * 8);
#pragma unroll
      for (int j = 0; j < 16; ++j) {
        bf16x8 b = *reinterpret_cast<const bf16x8*>(Bs + (j * 16 + lm) * 64 + so * 8);
        acc[0][j] = __builtin_amdgcn_mfma_f32_16x16x32_bf16(af[0], b, acc[0][j], 0, 0, 0);
        acc[1][j] = __builtin_amdgcn_mfma_f32_16x16x32_bf16(af[1], b, acc[1][j], 0, 0, 0);
      }
    }
    __syncthreads();
  }

  // epilogue: z = mu + exp(ls)*eps, kl rowsum
#pragma unroll
  for (int i = 0; i < 2; ++i) {
    float kl[4] = {0.f, 0.f, 0.f, 0.f};
#pragma unroll
    for (int j = 0; j < 8; ++j) {
      int dim = j * 16 + lm;
      float bm = bmu[dim], bl = bls[dim];
#pragma unroll
      for (int r = 0; r < 4; ++r) {
        int row = m0 + wave * 32 + i * 16 + lq * 4 + r;
        float mu = acc[i][j][r] + bm;
        float ls = acc[i][j + 8][r] + bl;
        float e = eps[(size_t)row * 128 + dim];
        z[(size_t)row * 128 + dim] = f32_to_bf16(fmaf(__expf(ls), e, mu));
        kl[r] += 0.5f * (__expf(2.f * ls) + mu * mu - 2.f * ls - 1.f);
      }
    }
#pragma unroll
    for (int off = 1; off < 16; off <<= 1)
#pragma unroll
      for (int r = 0; r < 4; ++r) kl[r] += __shfl_xor(kl[r], off, 64);
    if (lm == 0) {
#pragma unroll
      for (int r = 0; r < 4; ++r)
        out[m0 + wave * 32 + i * 16 + lq * 4 + r] = -kl[r];
    }
  }
}

extern "C" void kernel_launch(void* const* d_in, const int* in_sizes, int n_in,
                              void* d_out, int out_size, void* d_ws, size_t ws_size,
                              hipStream_t stream) {
  const float* x   = (const float*)d_in[0];
  const float* eps = (const float*)d_in[1];
  const float* We1 = (const float*)d_in[2];
  const float* be1 = (const float*)d_in[3];
  const float* Wmu = (const float*)d_in[4];
  const float* bmu = (const float*)d_in[5];
  const float* Wls = (const float*)d_in[6];
  const float* bls = (const float*)d_in[7];
  const float* Wd1 = (const float*)d_in[8];
  const float* bd1 = (const float*)d_in[9];
  const float* Wd2 = (const float*)d_in[10];
  const float* bd2 = (const float*)d_in[11];
  float* out = (float*)d_out;

  const int B = 32768, D = 1024, H = 1024, L = 128;

  char* ws = (char*)d_ws;
  size_t off = 0;
  auto alloc = [&](size_t bytes) {
    void* p = ws + off;
    off += (bytes + 255) & ~(size_t)255;
    return p;
  };
  unsigned short* xbf  = (unsigned short*)alloc((size_t)B * D * 2);   // 64 MB
  unsigned short* w1t  = (unsigned short*)alloc((size_t)H * D * 2);   // 2 MB  [H][D]
  unsigned short* w2t  = (unsigned short*)alloc((size_t)256 * H * 2); // 0.5MB [256][H]
  unsigned short* wd1t = (unsigned short*)alloc((size_t)H * L * 2);   // .25MB [H][L]
  unsigned short* wd2t = (unsigned short*)alloc((size_t)D * H * 2);   // 2 MB  [D][H]
  unsigned short* h    = (unsigned short*)alloc((size_t)B * H * 2);   // 64 MB
  unsigned short* z    = (unsigned short*)alloc((size_t)B * L * 2);   // 8 MB
  unsigned short* hd   = h;  // h is dead after gemm2_zkl -> reuse

  // prep: transposes (blocks 0..2432) + x cast (blocks 2432..4480)
  TransJob j0{We1, w1t, D, H, 1024};
  TransJob j1{Wmu, w2t, H, L, 1152};
  TransJob j2{Wls, w2t + 128 * H, H, L, 1280};
  TransJob j3{Wd1, wd1t, L, H, 1408};
  TransJob j4{Wd2, wd2t, H, D, 2432};
  prep_k<<<4480, dim3(32, 8), 0, stream>>>(j0, j1, j2, j3, j4, x, xbf, B * D / 4);

  // GEMM1: h = relu(x @ We1 + be1)   (gx = 1024/256 = 4, gy = 256)
  gemm_bt<0><<<4 * 256, 256, 0, stream>>>(
      xbf, w1t, 4, H, D, be1, h, nullptr, nullptr);
  // GEMM2 + z/kl fused (writes z and out[b] = -kl[b])
  gemm2_zkl<<<B / 128, 256, 0, stream>>>(h, w2t, H, bmu, bls, eps, z, out);
  // GEMM3: hd = relu(z @ Wd1 + bd1)
  gemm_bt<0><<<4 * 256, 256, 0, stream>>>(
      z, wd1t, 4, H, L, bd1, hd, nullptr, nullptr);
  // GEMM4: bernoulli log-likelihood accumulated into out
  gemm_bt<2><<<4 * 256, 256, 0, stream>>>(
      hd, wd2t, 4, D, H, bd2, nullptr, out, xbf);

  (void)in_sizes; (void)n_in; (void)out_size; (void)ws_size;
}

// Round 6
// 483.166 us; speedup vs baseline: 1.1704x; 1.1704x over previous
//
#include <hip/hip_runtime.h>
#include <cstdint>
#include <cstddef>

// VAE forward, fused bf16-MFMA pipeline.
// Sizes fixed: B=32768, INPUT=1024, HIDDEN=1024, LATENT=128.
//
// R6: (a) REVERT gemm_bt to R4 geometry (128x128 tile, BK=64). R5's 128x256
//     halved occupancy (20%->11%) and regressed 115->154us: barrier drain is
//     hidden only by cross-block overlap, so blocks/CU > per-iter amortization.
//     (b) gemm2_zkl re-tiled 128x256 -> 64x256 (512 blocks = 2/CU instead of
//     1/CU; 4 waves x 16 rows; LDS 40KB). The 1-block/CU version had zero
//     cross-block overlap -- every drain exposed.
// R5 (kept): fused prep kernel (5 transposes + x cast).
// R4 (kept): BK=64; gemm2+zkl fusion.
// R3 (kept): XCD-pinned 1D grid decode (FETCH 298->90MB).
// R2 (kept): XOR-swizzled staging (LDS bank conflicts -> 0).

typedef __bf16 bf16x8 __attribute__((ext_vector_type(8)));
typedef float f32x4 __attribute__((ext_vector_type(4)));

__device__ __forceinline__ unsigned short f32_to_bf16(float f) {
  unsigned int u = __float_as_uint(f);
  u += 0x7fffu + ((u >> 16) & 1u);   // round-to-nearest-even (finite values)
  return (unsigned short)(u >> 16);
}

// ------------- fused prep: 5 transposes + x-cast in one kernel -------------
struct TransJob { const float* in; unsigned short* out; int K, N, blkEnd; };

__global__ void prep_k(TransJob j0, TransJob j1, TransJob j2, TransJob j3,
                       TransJob j4, const float* __restrict__ x,
                       unsigned short* __restrict__ xbf, int n4) {
  int bid = blockIdx.x;
  int tid = threadIdx.y * 32 + threadIdx.x;
  if (bid >= 2432) {
    int base = (bid - 2432) * 256 + tid;
    int stride = 2048 * 256;
#pragma unroll
    for (int it = 0; it < 16; ++it) {
      int i = base + it * stride;
      float4 v = reinterpret_cast<const float4*>(x)[i];
      ushort4 o = make_ushort4(f32_to_bf16(v.x), f32_to_bf16(v.y),
                               f32_to_bf16(v.z), f32_to_bf16(v.w));
      reinterpret_cast<ushort4*>(xbf)[i] = o;
    }
    return;
  }
  __shared__ float tile[32][33];
  TransJob j; int base;
  if (bid < j0.blkEnd)      { j = j0; base = 0; }
  else if (bid < j1.blkEnd) { j = j1; base = j0.blkEnd; }
  else if (bid < j2.blkEnd) { j = j2; base = j1.blkEnd; }
  else if (bid < j3.blkEnd) { j = j3; base = j2.blkEnd; }
  else                      { j = j4; base = j3.blkEnd; }
  int local = bid - base;
  int gxN = j.N >> 5;
  int n0 = (local % gxN) * 32, k0 = (local / gxN) * 32;
  int tx = threadIdx.x, ty = threadIdx.y;  // block is 32x8
#pragma unroll
  for (int r = 0; r < 32; r += 8)
    tile[ty + r][tx] = j.in[(size_t)(k0 + ty + r) * j.N + n0 + tx];
  __syncthreads();
#pragma unroll
  for (int r = 0; r < 32; r += 8)
    j.out[(size_t)(n0 + ty + r) * j.K + k0 + tx] = f32_to_bf16(tile[tx][ty + r]);
}

// async global->LDS, 16B per lane; LDS dest must be contiguous in lane order
__device__ __forceinline__ void gl_lds16(const unsigned short* g, unsigned short* l) {
  __builtin_amdgcn_global_load_lds(
      (__attribute__((address_space(1))) void*)g,
      (__attribute__((address_space(3))) void*)l, 16, 0, 0);
}

// ---------------- GEMM: C = A[M][K] @ BT[N][K]^T + bias, 128x128 tile, BK=64 ----------------
// 1D grid, XCD-pinned decode. EPI 0: relu->bf16. EPI 2: bernoulli LL rowsum atomicAdd.
template <int EPI>
__global__ __launch_bounds__(256) void gemm_bt(
    const unsigned short* __restrict__ A, const unsigned short* __restrict__ BT,
    int gx, int N, int K,
    const float* __restrict__ bias0,
    unsigned short* __restrict__ outb, float* __restrict__ outf,
    const unsigned short* __restrict__ xbf) {
  __shared__ __align__(16) unsigned short As[128 * 64];   // 16 KB
  __shared__ __align__(16) unsigned short Bs[128 * 64];   // 16 KB

  const int tid = threadIdx.x;
  const int lane = tid & 63;
  const int wave = tid >> 6;
  const int wr = wave >> 1, wc = wave & 1;   // 64x64 quadrant
  const int bid = blockIdx.x;
  const int xcd = bid & 7;
  const int t8 = bid >> 3;
  const int m0 = (xcd + 8 * (t8 / gx)) * 128;
  const int n0 = (t8 % gx) * 128;
  const int lm = lane & 15, lq = lane >> 4;

  // staging: 1024 16B-chunks per tile -> 4 per thread; chunk c: row=c>>3,
  // LDS slot c&7 holds global chunk (c&7)^(row&7)
  const unsigned short* agp[4];
  const unsigned short* bgp[4];
#pragma unroll
  for (int r = 0; r < 4; ++r) {
    int c = tid + 256 * r;
    int row = c >> 3, q = (c & 7) ^ (row & 7);
    agp[r] = A + (size_t)(m0 + row) * K + q * 8;
    bgp[r] = BT + (size_t)(n0 + row) * K + q * 8;
  }
  const int sw = lm & 7;   // read-side swizzle

  f32x4 acc[4][4] = {};

  for (int kt = 0; kt < K; kt += 64) {
#pragma unroll
    for (int r = 0; r < 4; ++r) {
      gl_lds16(agp[r] + kt, As + (tid + 256 * r) * 8);
      gl_lds16(bgp[r] + kt, Bs + (tid + 256 * r) * 8);
    }
    __syncthreads();

#pragma unroll
    for (int s = 0; s < 2; ++s) {
      const int so = ((s << 2) | lq) ^ sw;
      bf16x8 af[4], bfr[4];
#pragma unroll
      for (int i = 0; i < 4; ++i)
        af[i] = *reinterpret_cast<const bf16x8*>(As + (wr * 64 + i * 16 + lm) * 64 + so * 8);
#pragma unroll
      for (int j = 0; j < 4; ++j)
        bfr[j] = *reinterpret_cast<const bf16x8*>(Bs + (wc * 64 + j * 16 + lm) * 64 + so * 8);
#pragma unroll
      for (int i = 0; i < 4; ++i)
#pragma unroll
        for (int j = 0; j < 4; ++j)
          acc[i][j] = __builtin_amdgcn_mfma_f32_16x16x32_bf16(af[i], bfr[j], acc[i][j], 0, 0, 0);
    }
    __syncthreads();
  }

  if (EPI == 0) {
#pragma unroll
    for (int i = 0; i < 4; ++i)
#pragma unroll
      for (int j = 0; j < 4; ++j) {
        int col = n0 + wc * 64 + j * 16 + lm;
        float bias = bias0[col];
#pragma unroll
        for (int r = 0; r < 4; ++r) {
          int row = m0 + wr * 64 + i * 16 + lq * 4 + r;
          float v = acc[i][j][r] + bias;
          v = fmaxf(v, 0.f);
          outb[(size_t)row * N + col] = f32_to_bf16(v);
        }
      }
  } else {
#pragma unroll
    for (int i = 0; i < 4; ++i) {
      float rs[4] = {0.f, 0.f, 0.f, 0.f};
#pragma unroll
      for (int j = 0; j < 4; ++j) {
        int col = n0 + wc * 64 + j * 16 + lm;
        float bias = bias0[col];
#pragma unroll
        for (int r = 0; r < 4; ++r) {
          int row = m0 + wr * 64 + i * 16 + lq * 4 + r;
          float l = acc[i][j][r] + bias;
          unsigned short xb = xbf[(size_t)row * N + col];  // 0x0000 or 0x3F80
          float t = xb ? -l : l;
          float sp = fmaxf(t, 0.f) + __logf(1.f + __expf(-fabsf(t)));
          rs[r] -= sp;
        }
      }
#pragma unroll
      for (int off = 1; off < 16; off <<= 1)
#pragma unroll
        for (int r = 0; r < 4; ++r) rs[r] += __shfl_xor(rs[r], off, 64);
      if (lm == 0) {
#pragma unroll
        for (int r = 0; r < 4; ++r)
          atomicAdd(&outf[m0 + wr * 64 + i * 16 + lq * 4 + r], rs[r]);
      }
    }
  }
}

// -------- GEMM2+zkl fused: S2 = h @ w2t^T (N=256), z/kl in epilogue --------
// 64x256 tile per block (512 blocks = 2/CU), 4 waves each 16 rows x 256 cols.
// acc[j]: mu at n-tile j (j<8), ls at j+8 -> same lane, no cross-lane.
__global__ __launch_bounds__(256) void gemm2_zkl(
    const unsigned short* __restrict__ A,     // h [B][K]
    const unsigned short* __restrict__ BT,    // w2t [256][K]
    int K,
    const float* __restrict__ bmu, const float* __restrict__ bls,
    const float* __restrict__ eps,            // [B][128]
    unsigned short* __restrict__ z,           // [B][128] bf16
    float* __restrict__ out) {
  __shared__ __align__(16) unsigned short As[64 * 64];    //  8 KB
  __shared__ __align__(16) unsigned short Bs[256 * 64];   // 32 KB

  const int tid = threadIdx.x;
  const int lane = tid & 63;
  const int wave = tid >> 6;
  const int m0 = blockIdx.x * 64;
  const int lm = lane & 15, lq = lane >> 4;

  // A: 512 chunks (2/thread); B: 2048 chunks (8/thread)
  const unsigned short* agp[2];
  const unsigned short* bgp[8];
#pragma unroll
  for (int r = 0; r < 2; ++r) {
    int c = tid + 256 * r;
    int row = c >> 3, q = (c & 7) ^ (row & 7);
    agp[r] = A + (size_t)(m0 + row) * K + q * 8;
  }
#pragma unroll
  for (int r = 0; r < 8; ++r) {
    int c = tid + 256 * r;
    int row = c >> 3, q = (c & 7) ^ (row & 7);
    bgp[r] = BT + (size_t)row * K + q * 8;
  }
  const int sw = lm & 7;

  f32x4 acc[16] = {};

  for (int kt = 0; kt < K; kt += 64) {
#pragma unroll
    for (int r = 0; r < 2; ++r) gl_lds16(agp[r] + kt, As + (tid + 256 * r) * 8);
#pragma unroll
    for (int r = 0; r < 8; ++r) gl_lds16(bgp[r] + kt, Bs + (tid + 256 * r) * 8);
    __syncthreads();

#pragma unroll
    for (int s = 0; s < 2; ++s) {
      const int so = ((s << 2) | lq) ^ sw;
      bf16x8 af = *reinterpret_cast<const bf16x8*>(As + (wave * 16 + lm) * 64 + so * 8);
#pragma unroll
      for (int j = 0; j < 16; ++j) {
        bf16x8 b = *reinterpret_cast<const bf16x8*>(Bs + (j * 16 + lm) * 64 + so * 8);
        acc[j] = __builtin_amdgcn_mfma_f32_16x16x32_bf16(af, b, acc[j], 0, 0, 0);
      }
    }
    __syncthreads();
  }

  // epilogue: z = mu + exp(ls)*eps, kl rowsum
  float kl[4] = {0.f, 0.f, 0.f, 0.f};
#pragma unroll
  for (int j = 0; j < 8; ++j) {
    int dim = j * 16 + lm;
    float bm = bmu[dim], bl = bls[dim];
#pragma unroll
    for (int r = 0; r < 4; ++r) {
      int row = m0 + wave * 16 + lq * 4 + r;
      float mu = acc[j][r] + bm;
      float ls = acc[j + 8][r] + bl;
      float e = eps[(size_t)row * 128 + dim];
      z[(size_t)row * 128 + dim] = f32_to_bf16(fmaf(__expf(ls), e, mu));
      kl[r] += 0.5f * (__expf(2.f * ls) + mu * mu - 2.f * ls - 1.f);
    }
  }
#pragma unroll
  for (int off = 1; off < 16; off <<= 1)
#pragma unroll
    for (int r = 0; r < 4; ++r) kl[r] += __shfl_xor(kl[r], off, 64);
  if (lm == 0) {
#pragma unroll
    for (int r = 0; r < 4; ++r)
      out[m0 + wave * 16 + lq * 4 + r] = -kl[r];
  }
}

extern "C" void kernel_launch(void* const* d_in, const int* in_sizes, int n_in,
                              void* d_out, int out_size, void* d_ws, size_t ws_size,
                              hipStream_t stream) {
  const float* x   = (const float*)d_in[0];
  const float* eps = (const float*)d_in[1];
  const float* We1 = (const float*)d_in[2];
  const float* be1 = (const float*)d_in[3];
  const float* Wmu = (const float*)d_in[4];
  const float* bmu = (const float*)d_in[5];
  const float* Wls = (const float*)d_in[6];
  const float* bls = (const float*)d_in[7];
  const float* Wd1 = (const float*)d_in[8];
  const float* bd1 = (const float*)d_in[9];
  const float* Wd2 = (const float*)d_in[10];
  const float* bd2 = (const float*)d_in[11];
  float* out = (float*)d_out;

  const int B = 32768, D = 1024, H = 1024, L = 128;

  char* ws = (char*)d_ws;
  size_t off = 0;
  auto alloc = [&](size_t bytes) {
    void* p = ws + off;
    off += (bytes + 255) & ~(size_t)255;
    return p;
  };
  unsigned short* xbf  = (unsigned short*)alloc((size_t)B * D * 2);   // 64 MB
  unsigned short* w1t  = (unsigned short*)alloc((size_t)H * D * 2);   // 2 MB  [H][D]
  unsigned short* w2t  = (unsigned short*)alloc((size_t)256 * H * 2); // 0.5MB [256][H]
  unsigned short* wd1t = (unsigned short*)alloc((size_t)H * L * 2);   // .25MB [H][L]
  unsigned short* wd2t = (unsigned short*)alloc((size_t)D * H * 2);   // 2 MB  [D][H]
  unsigned short* h    = (unsigned short*)alloc((size_t)B * H * 2);   // 64 MB
  unsigned short* z    = (unsigned short*)alloc((size_t)B * L * 2);   // 8 MB
  unsigned short* hd   = h;  // h is dead after gemm2_zkl -> reuse

  // prep: transposes (blocks 0..2432) + x cast (blocks 2432..4480)
  TransJob j0{We1, w1t, D, H, 1024};
  TransJob j1{Wmu, w2t, H, L, 1152};
  TransJob j2{Wls, w2t + 128 * H, H, L, 1280};
  TransJob j3{Wd1, wd1t, L, H, 1408};
  TransJob j4{Wd2, wd2t, H, D, 2432};
  prep_k<<<4480, dim3(32, 8), 0, stream>>>(j0, j1, j2, j3, j4, x, xbf, B * D / 4);

  // GEMM1: h = relu(x @ We1 + be1)
  gemm_bt<0><<<8 * 256, 256, 0, stream>>>(
      xbf, w1t, 8, H, D, be1, h, nullptr, nullptr);
  // GEMM2 + z/kl fused (writes z and out[b] = -kl[b])
  gemm2_zkl<<<B / 64, 256, 0, stream>>>(h, w2t, H, bmu, bls, eps, z, out);
  // GEMM3: hd = relu(z @ Wd1 + bd1)
  gemm_bt<0><<<8 * 256, 256, 0, stream>>>(
      z, wd1t, 8, H, L, bd1, hd, nullptr, nullptr);
  // GEMM4: bernoulli log-likelihood accumulated into out
  gemm_bt<2><<<8 * 256, 256, 0, stream>>>(
      hd, wd2t, 8, D, H, bd2, nullptr, out, xbf);

  (void)in_sizes; (void)n_in; (void)out_size; (void)ws_size;
}